// Round 4
// baseline (270.323 us; speedup 1.0000x reference)
//
#include <hip/hip_runtime.h>
#include <hip/hip_bf16.h>

#define AS1 __attribute__((address_space(1)))
#define AS3 __attribute__((address_space(3)))

typedef unsigned short u16;
typedef short bf16x8 __attribute__((ext_vector_type(8)));
typedef unsigned short u16x8 __attribute__((ext_vector_type(8)));
typedef float f32x4 __attribute__((ext_vector_type(4)));

#define MFMA16 __builtin_amdgcn_mfma_f32_16x16x32_bf16

// ---------------- helpers ----------------

__device__ __forceinline__ u16 f2bf(float f) {        // RNE (finite data)
  union { float f; unsigned u; } c; c.f = f;
  unsigned u = c.u;
  u = u + 0x7fffu + ((u >> 16) & 1u);
  return (u16)(u >> 16);
}

__device__ __forceinline__ u16 f2bf_trunc(float f) {  // truncation: P-weights only
  union { float f; unsigned u; } c; c.f = f;
  return (u16)(c.u >> 16);
}

__device__ __forceinline__ void gl_lds16(const void* g, void* l) {
  __builtin_amdgcn_global_load_lds((const AS1 void*)g, (AS3 void*)l, 16, 0, 0);
}

// ---------------- cast fp32 -> bf16, with 64-col-tile granule swizzle ----------------

__global__ void cast_all_kernel(const float* __restrict__ x,
                                const float* __restrict__ wqkv,
                                const float* __restrict__ wout,
                                u16* __restrict__ ws) {
  int i = blockIdx.x * blockDim.x + threadIdx.x;   // float4 index, 3145728 total
  const float4* src;
  int rel;
  size_t matbase;
  if (i < 2097152)      { src = (const float4*)x + i;                rel = i;           matbase = 0; }
  else if (i < 2883584) { src = (const float4*)wqkv + (i - 2097152); rel = i - 2097152; matbase = 8388608; }
  else                  { src = (const float4*)wout + (i - 2883584); rel = i - 2883584; matbase = 11534336; }
  float4 f = *src;
  ushort4 o;
  o.x = f2bf(f.x); o.y = f2bf(f.y); o.z = f2bf(f.z); o.w = f2bf(f.w);
  int fe  = rel * 4;
  int row = fe >> 10, c = fe & 1023;
  int newc = (c & ~63) | (((((c >> 3) ^ row) & 7) << 3)) | (c & 7);
  ((ushort4*)ws)[(matbase + (size_t)row * 1024 + newc) >> 2] = o;
}

// ---------------- GEMM: C[M,N] = A[M,K] * B[N,K]^T  (bf16 in, fp32 acc) ----------------

template<int EPI>
__global__ __launch_bounds__(256) void gemm_bt(
    const u16* __restrict__ A, const u16* __restrict__ Bm,
    float* __restrict__ Cf,
    u16* __restrict__ qd, u16* __restrict__ kd, u16* __restrict__ vd,
    int M, int N, int K)
{
  __shared__ u16 As[128 * 64];
  __shared__ u16 Bs[128 * 64];

  const int tid  = threadIdx.x;
  const int wave = tid >> 6, lane = tid & 63;
  const int quad = lane >> 4, l16 = lane & 15;
  const int bm = blockIdx.y * 128, bn = blockIdx.x * 128;
  const int wm = (wave >> 1) * 64, wn = (wave & 1) * 64;

  f32x4 acc[4][4] = {};

  const int srow = wave * 32 + (lane >> 3);
  const int scol = (lane & 7) * 8;

  for (int kt = 0; kt < K; kt += 64) {
    __syncthreads();
    #pragma unroll
    for (int i = 0; i < 4; ++i) {
      gl_lds16(&A[(size_t)(bm + srow + i * 8) * K + kt + scol], &As[(wave * 32 + i * 8) * 64]);
      gl_lds16(&Bm[(size_t)(bn + srow + i * 8) * K + kt + scol], &Bs[(wave * 32 + i * 8) * 64]);
    }
    __syncthreads();
    #pragma unroll
    for (int kk = 0; kk < 64; kk += 32) {
      bf16x8 af[4], bb[4];
      #pragma unroll
      for (int i = 0; i < 4; ++i) {
        int row = wm + i * 16 + l16;
        af[i] = *(const bf16x8*)&As[row * 64 + (((((kk >> 3) + quad) ^ row) & 7) << 3)];
      }
      #pragma unroll
      for (int j = 0; j < 4; ++j) {
        int row = wn + j * 16 + l16;
        bb[j] = *(const bf16x8*)&Bs[row * 64 + (((((kk >> 3) + quad) ^ row) & 7) << 3)];
      }
      #pragma unroll
      for (int i = 0; i < 4; ++i)
        #pragma unroll
        for (int j = 0; j < 4; ++j)
          acc[i][j] = MFMA16(af[i], bb[j], acc[i][j], 0, 0, 0);
    }
  }

  #pragma unroll
  for (int i = 0; i < 4; ++i) {
    #pragma unroll
    for (int j = 0; j < 4; ++j) {
      #pragma unroll
      for (int r = 0; r < 4; ++r) {
        int m = bm + wm + i * 16 + quad * 4 + r;
        int n = bn + wn + j * 16 + l16;
        float val = acc[i][j][r];
        if (EPI == 0) {
          Cf[(size_t)m * N + n] = val;
        } else {
          int part = n >> 10, rem = n & 1023;
          int h = rem >> 6, d = rem & 63;
          int b = m >> 12, s = m & 4095;
          if (part == 0) val *= 0.1803368801111244f;   // 0.125 * log2(e), exp2 path
          u16* dst = (part == 0) ? qd : (part == 1) ? kd : vd;
          dst[((size_t)((b * 16 + h) * 4096 + s)) * 64 + d] = f2bf(val);
        }
      }
    }
  }
}

// ---------------- V transpose: [B,H,S,64] -> [B,H,64,S] ----------------
// XCD swizzle: bh = bid&31 so vt writes stay in the consuming XCD's L2.

__global__ __launch_bounds__(256) void transpose_v(const u16* __restrict__ vb,
                                                   u16* __restrict__ vt) {
  __shared__ u16 Lt[64 * 72];
  const int tid = threadIdx.x, bid = blockIdx.x;
  const int bh = bid & 31, st = (bid >> 5) << 6;
  const size_t base = (size_t)bh << 18;
  #pragma unroll
  for (int c = 0; c < 2; ++c) {
    int idx = tid * 8 + c * 2048;
    int row = idx >> 6, col = idx & 63;
    u16x8 vv = *(const u16x8*)&vb[base + (size_t)(st + row) * 64 + col];
    #pragma unroll
    for (int s = 0; s < 8; ++s) Lt[(col + s) * 72 + row] = vv[s];
  }
  __syncthreads();
  #pragma unroll
  for (int c = 0; c < 2; ++c) {
    int d = (tid >> 3) + c * 32;
    int sg = (tid & 7) * 8;
    u16x8 o;
    #pragma unroll
    for (int s = 0; s < 8; ++s) o[s] = Lt[d * 72 + sg + s];
    *(u16x8*)&vt[base + (size_t)d * 4096 + st + sg] = o;
  }
}

// ---------------- attention: zero-barrier, one wave per 32 query rows ----------------
// XCD-locality swizzle: bh = bid & 31 (bid%8 = bh%8 -> all tiles of a head on one XCD,
// concurrent blocks walk tiles in lock-step -> K/V window L2-resident, HBM-once).

__global__ __launch_bounds__(64) void attn_kernel(
    const u16* __restrict__ qb, const u16* __restrict__ kb,
    const u16* __restrict__ vt, u16* __restrict__ ob)
{
  __shared__ u16 Ps[32 * 64];

  const int lane = threadIdx.x;
  const int quad = lane >> 4, l16 = lane & 15;
  const int bid  = blockIdx.x;
  const int bh   = bid & 31;
  const int t0   = (bid >> 5) << 5;
  const size_t base = (size_t)bh << 18;

  // Q A-fragments (A[m=l16][k=quad*8+j])
  bf16x8 aq[2][2];
  #pragma unroll
  for (int i = 0; i < 2; ++i) {
    const u16* qrow = qb + base + (size_t)(t0 + i * 16 + l16) * 64;
    aq[i][0] = *(const bf16x8*)(qrow + quad * 8);
    aq[i][1] = *(const bf16x8*)(qrow + 32 + quad * 8);
  }

  f32x4 oacc[2][4] = {};
  f32x4 lacc[2] = {};
  bf16x8 ones;
  #pragma unroll
  for (int s = 0; s < 8; ++s) ones[s] = (short)0x3F80;

  // ======== prefix tile (keys 0..15, causal) ========
  {
    const u16* krow = kb + base + (size_t)l16 * 64;     // keys 0..15
    bf16x8 bk0 = *(const bf16x8*)(krow + quad * 8);
    bf16x8 bk1 = *(const bf16x8*)(krow + 32 + quad * 8);
    #pragma unroll
    for (int i = 0; i < 2; ++i) {
      f32x4 t4 = {};
      t4 = MFMA16(aq[i][0], bk0, t4, 0, 0, 0);
      t4 = MFMA16(aq[i][1], bk1, t4, 0, 0, 0);
      #pragma unroll
      for (int r = 0; r < 4; ++r) {
        int qpos = t0 + i * 16 + quad * 4 + r;
        float v = (l16 <= qpos) ? t4[r] : -1e30f;
        float p = exp2f(v);
        int row = i * 16 + quad * 4 + r;
        int gp = ((l16 >> 3) ^ row) & 7;
        Ps[row * 64 + (gp << 3) + (l16 & 7)] = f2bf_trunc(p);
        int gz = ((2 + (l16 >> 3)) ^ row) & 7;
        Ps[row * 64 + (gz << 3) + (l16 & 7)] = 0;
      }
    }
    bf16x8 ap[2];
    #pragma unroll
    for (int i = 0; i < 2; ++i) {
      int rowp = i * 16 + l16;
      int gb = (quad ^ rowp) & 7;
      ap[i] = *(const bf16x8*)&Ps[rowp * 64 + (gb << 3)];
      lacc[i] = MFMA16(ap[i], ones, lacc[i], 0, 0, 0);
    }
    #pragma unroll
    for (int jd = 0; jd < 4; ++jd) {
      const u16* vrow = vt + base + (size_t)(jd * 16 + l16) * 4096;
      bf16x8 bv0 = *(const bf16x8*)(vrow + quad * 8);
      #pragma unroll
      for (int i = 0; i < 2; ++i)
        oacc[i][jd] = MFMA16(ap[i], bv0, oacc[i][jd], 0, 0, 0);
    }
  }

  // ======== sliding-window tiles ========
  const int lo = max(0, t0 - 511) >> 6;
  const int hi = (t0 + 31) >> 6;

  for (int t = lo; t <= hi; ++t) {
    const int kb0 = t << 6;
    const bool full = (kb0 >= 16) && (kb0 + 63 <= t0) && (kb0 >= t0 + 31 - 511);

    #pragma unroll
    for (int j = 0; j < 4; ++j) {
      const u16* krow = kb + base + (size_t)(kb0 + j * 16 + l16) * 64;
      bf16x8 bk0 = *(const bf16x8*)(krow + quad * 8);
      bf16x8 bk1 = *(const bf16x8*)(krow + 32 + quad * 8);
      #pragma unroll
      for (int i = 0; i < 2; ++i) {
        f32x4 t4 = {};
        t4 = MFMA16(aq[i][0], bk0, t4, 0, 0, 0);
        t4 = MFMA16(aq[i][1], bk1, t4, 0, 0, 0);
        #pragma unroll
        for (int r = 0; r < 4; ++r) {
          float v = t4[r];
          if (!full) {
            int kpos = kb0 + j * 16 + l16;
            int qpos = t0 + i * 16 + quad * 4 + r;
            int diff = qpos - kpos;
            bool ok = (diff >= 0) && (diff < 512) && (kpos >= 16);
            v = ok ? v : -1e30f;
          }
          float p = exp2f(v);
          int row = i * 16 + quad * 4 + r;
          int gp = ((2 * j + (l16 >> 3)) ^ row) & 7;
          Ps[row * 64 + (gp << 3) + (l16 & 7)] = f2bf_trunc(p);
        }
      }
    }

    bf16x8 ap[2][2];
    #pragma unroll
    for (int i = 0; i < 2; ++i) {
      int rowp = i * 16 + l16;
      int gb = (quad ^ rowp) & 7;
      ap[i][0] = *(const bf16x8*)&Ps[rowp * 64 + (gb << 3)];
      ap[i][1] = *(const bf16x8*)&Ps[rowp * 64 + ((gb ^ 4) << 3)];
      lacc[i] = MFMA16(ap[i][0], ones, lacc[i], 0, 0, 0);
      lacc[i] = MFMA16(ap[i][1], ones, lacc[i], 0, 0, 0);
    }
    #pragma unroll
    for (int jd = 0; jd < 4; ++jd) {
      const u16* vrow = vt + base + (size_t)(jd * 16 + l16) * 4096 + kb0;
      bf16x8 bv0 = *(const bf16x8*)(vrow + quad * 8);
      bf16x8 bv1 = *(const bf16x8*)(vrow + 32 + quad * 8);
      #pragma unroll
      for (int i = 0; i < 2; ++i) {
        oacc[i][jd] = MFMA16(ap[i][0], bv0, oacc[i][jd], 0, 0, 0);
        oacc[i][jd] = MFMA16(ap[i][1], bv1, oacc[i][jd], 0, 0, 0);
      }
    }
  }

  // ---- epilogue: O/l -> bf16 [B,S,H*64], granule-swizzled for GEMM3 staging ----
  const int b = bh >> 4, h = bh & 15;
  #pragma unroll
  for (int i = 0; i < 2; ++i) {
    #pragma unroll
    for (int r = 0; r < 4; ++r) {
      float inv = 1.f / lacc[i][r];
      int srow = t0 + i * 16 + quad * 4 + r;
      size_t rowoff = ((size_t)(b * 4096 + srow)) * 1024 + h * 64;
      #pragma unroll
      for (int jd = 0; jd < 4; ++jd) {
        int g = ((jd * 2 + (l16 >> 3)) ^ srow) & 7;
        ob[rowoff + (g << 3) + (l16 & 7)] = f2bf(oacc[i][jd][r] * inv);
      }
    }
  }
}

// ---------------- launch ----------------

extern "C" void kernel_launch(void* const* d_in, const int* in_sizes, int n_in,
                              void* d_out, int out_size, void* d_ws, size_t ws_size,
                              hipStream_t stream) {
  const float* x    = (const float*)d_in[0];
  const float* wqkv = (const float*)d_in[1];
  const float* wout = (const float*)d_in[2];
  float* out = (float*)d_out;

  u16* ws    = (u16*)d_ws;
  u16* xb    = ws;                                   // 8192*1024  (reused as obuf)
  u16* wqkvb = xb + (size_t)8192 * 1024;             // 3072*1024
  u16* woutb = wqkvb + (size_t)3072 * 1024;          // 1024*1024
  u16* qbuf  = woutb + (size_t)1024 * 1024;          // [2,16,4096,64]
  u16* kbuf  = qbuf + (size_t)8388608;
  u16* vbuf  = kbuf + (size_t)8388608;
  u16* vtb   = vbuf + (size_t)8388608;               // [2,16,64,4096]
  u16* obuf  = xb;                                   // alias: xb dead after gemm1

  cast_all_kernel<<<12288, 256, 0, stream>>>(x, wqkv, wout, ws);

  gemm_bt<1><<<dim3(24, 64), 256, 0, stream>>>(xb, wqkvb, nullptr, qbuf, kbuf, vbuf,
                                               8192, 3072, 1024);
  transpose_v<<<2048, 256, 0, stream>>>(vbuf, vtb);
  attn_kernel<<<4096, 64, 0, stream>>>(qbuf, kbuf, vtb, obuf);
  gemm_bt<0><<<dim3(8, 64), 256, 0, stream>>>(obuf, woutb, out, nullptr, nullptr, nullptr,
                                              8192, 1024, 1024);
}

// Round 5
// 265.247 us; speedup vs baseline: 1.0191x; 1.0191x over previous
//
#include <hip/hip_runtime.h>
#include <hip/hip_bf16.h>

#define AS1 __attribute__((address_space(1)))
#define AS3 __attribute__((address_space(3)))

typedef unsigned short u16;
typedef short bf16x8 __attribute__((ext_vector_type(8)));
typedef unsigned short u16x8 __attribute__((ext_vector_type(8)));
typedef float f32x4 __attribute__((ext_vector_type(4)));

#define MFMA16 __builtin_amdgcn_mfma_f32_16x16x32_bf16

// ---------------- helpers ----------------

__device__ __forceinline__ u16 f2bf(float f) {        // RNE (finite data)
  union { float f; unsigned u; } c; c.f = f;
  unsigned u = c.u;
  u = u + 0x7fffu + ((u >> 16) & 1u);
  return (u16)(u >> 16);
}

__device__ __forceinline__ void gl_lds16(const void* g, void* l) {
  __builtin_amdgcn_global_load_lds((const AS1 void*)g, (AS3 void*)l, 16, 0, 0);
}

union fpu { float f; unsigned u; };

// ---------------- cast fp32 -> bf16, with 64-col-tile granule swizzle ----------------

__global__ void cast_all_kernel(const float* __restrict__ x,
                                const float* __restrict__ wqkv,
                                const float* __restrict__ wout,
                                u16* __restrict__ ws) {
  int i = blockIdx.x * blockDim.x + threadIdx.x;   // float4 index, 3145728 total
  const float4* src;
  int rel;
  size_t matbase;
  if (i < 2097152)      { src = (const float4*)x + i;                rel = i;           matbase = 0; }
  else if (i < 2883584) { src = (const float4*)wqkv + (i - 2097152); rel = i - 2097152; matbase = 8388608; }
  else                  { src = (const float4*)wout + (i - 2883584); rel = i - 2883584; matbase = 11534336; }
  float4 f = *src;
  ushort4 o;
  o.x = f2bf(f.x); o.y = f2bf(f.y); o.z = f2bf(f.z); o.w = f2bf(f.w);
  int fe  = rel * 4;
  int row = fe >> 10, c = fe & 1023;
  int newc = (c & ~63) | (((((c >> 3) ^ row) & 7) << 3)) | (c & 7);
  ((ushort4*)ws)[(matbase + (size_t)row * 1024 + newc) >> 2] = o;
}

// ---------------- GEMM: C[M,N] = A[M,K] * B[N,K]^T  (bf16 in, fp32 acc) ----------------

template<int EPI>
__global__ __launch_bounds__(256) void gemm_bt(
    const u16* __restrict__ A, const u16* __restrict__ Bm,
    float* __restrict__ Cf,
    u16* __restrict__ qd, u16* __restrict__ kd, u16* __restrict__ vd,
    int M, int N, int K)
{
  __shared__ u16 As[128 * 64];
  __shared__ u16 Bs[128 * 64];

  const int tid  = threadIdx.x;
  const int wave = tid >> 6, lane = tid & 63;
  const int quad = lane >> 4, l16 = lane & 15;
  const int bm = blockIdx.y * 128, bn = blockIdx.x * 128;
  const int wm = (wave >> 1) * 64, wn = (wave & 1) * 64;

  f32x4 acc[4][4] = {};

  const int srow = wave * 32 + (lane >> 3);
  const int scol = (lane & 7) * 8;

  for (int kt = 0; kt < K; kt += 64) {
    __syncthreads();
    #pragma unroll
    for (int i = 0; i < 4; ++i) {
      gl_lds16(&A[(size_t)(bm + srow + i * 8) * K + kt + scol], &As[(wave * 32 + i * 8) * 64]);
      gl_lds16(&Bm[(size_t)(bn + srow + i * 8) * K + kt + scol], &Bs[(wave * 32 + i * 8) * 64]);
    }
    __syncthreads();
    #pragma unroll
    for (int kk = 0; kk < 64; kk += 32) {
      bf16x8 af[4], bb[4];
      #pragma unroll
      for (int i = 0; i < 4; ++i) {
        int row = wm + i * 16 + l16;
        af[i] = *(const bf16x8*)&As[row * 64 + (((((kk >> 3) + quad) ^ row) & 7) << 3)];
      }
      #pragma unroll
      for (int j = 0; j < 4; ++j) {
        int row = wn + j * 16 + l16;
        bb[j] = *(const bf16x8*)&Bs[row * 64 + (((((kk >> 3) + quad) ^ row) & 7) << 3)];
      }
      #pragma unroll
      for (int i = 0; i < 4; ++i)
        #pragma unroll
        for (int j = 0; j < 4; ++j)
          acc[i][j] = MFMA16(af[i], bb[j], acc[i][j], 0, 0, 0);
    }
  }

  #pragma unroll
  for (int i = 0; i < 4; ++i) {
    #pragma unroll
    for (int j = 0; j < 4; ++j) {
      #pragma unroll
      for (int r = 0; r < 4; ++r) {
        int m = bm + wm + i * 16 + quad * 4 + r;
        int n = bn + wn + j * 16 + l16;
        float val = acc[i][j][r];
        if (EPI == 0) {
          Cf[(size_t)m * N + n] = val;
        } else {
          int part = n >> 10, rem = n & 1023;
          int h = rem >> 6, d = rem & 63;
          int b = m >> 12, s = m & 4095;
          if (part == 0) val *= 0.1803368801111244f;   // 0.125 * log2(e), exp2 path
          u16* dst = (part == 0) ? qd : (part == 1) ? kd : vd;
          dst[((size_t)((b * 16 + h) * 4096 + s)) * 64 + d] = f2bf(val);
        }
      }
    }
  }
}

// ---------------- V transpose: [B,H,S,64] -> [B,H,64,S] ----------------

__global__ __launch_bounds__(256) void transpose_v(const u16* __restrict__ vb,
                                                   u16* __restrict__ vt) {
  __shared__ u16 Lt[64 * 72];
  const int tid = threadIdx.x, bid = blockIdx.x;
  const int bh = bid & 31, st = (bid >> 5) << 6;
  const size_t base = (size_t)bh << 18;
  #pragma unroll
  for (int c = 0; c < 2; ++c) {
    int idx = tid * 8 + c * 2048;
    int row = idx >> 6, col = idx & 63;
    u16x8 vv = *(const u16x8*)&vb[base + (size_t)(st + row) * 64 + col];
    #pragma unroll
    for (int s = 0; s < 8; ++s) Lt[(col + s) * 72 + row] = vv[s];
  }
  __syncthreads();
  #pragma unroll
  for (int c = 0; c < 2; ++c) {
    int d = (tid >> 3) + c * 32;
    int sg = (tid & 7) * 8;
    u16x8 o;
    #pragma unroll
    for (int s = 0; s < 8; ++s) o[s] = Lt[d * 72 + sg + s];
    *(u16x8*)&vt[base + (size_t)d * 4096 + st + sg] = o;
  }
}

// ---------------- attention: zero-barrier, S^T trick, K-prefetch pipeline ----------------
// S^T = K·Q^T via MFMA(A=K, B=Q): C-layout regs r=0..3 are 4 consecutive KEYS of one
// query -> P staged as packed ds_write_b64. Ps[query row][key], 8B granule (4 keys),
// 4-bit XOR swizzle g' = g ^ (row&15): bank-optimal writes AND reads.
// K fragments double-buffered one tile ahead (manual unroll-by-2 keeps regs).

__global__ __launch_bounds__(64) void attn_kernel(
    const u16* __restrict__ qb, const u16* __restrict__ kb,
    const u16* __restrict__ vt, u16* __restrict__ ob)
{
  __shared__ u16 Ps[32 * 64];

  const int lane = threadIdx.x;
  const int quad = lane >> 4, l16 = lane & 15;
  const int bid  = blockIdx.x;
  const int bh   = bid & 31;
  const int t0   = (bid >> 5) << 5;
  const size_t base = (size_t)bh << 18;

  // Q B-fragments (B[n=query l16][k=dh quad*8+j]); q pre-scaled by 0.125*log2e
  bf16x8 bq[2][2];
  #pragma unroll
  for (int i = 0; i < 2; ++i) {
    const u16* qrow = qb + base + (size_t)(t0 + i * 16 + l16) * 64;
    bq[i][0] = *(const bf16x8*)(qrow + quad * 8);
    bq[i][1] = *(const bf16x8*)(qrow + 32 + quad * 8);
  }

  f32x4 oacc[2][4] = {};
  f32x4 lacc[2] = {};
  bf16x8 ones;
  #pragma unroll
  for (int s = 0; s < 8; ++s) ones[s] = (short)0x3F80;

  const int lo = max(0, t0 - 511) >> 6;
  const int hi = (t0 + 31) >> 6;

  // K A-frag loader: A[m=key l16][k=dh quad*8+..], per j-subtile, 2 dh-halves
  auto loadK = [&](int kb0, bf16x8 (&kf)[4][2]) {
    #pragma unroll
    for (int j = 0; j < 4; ++j) {
      const u16* krow = kb + base + (size_t)(kb0 + j * 16 + l16) * 64;
      kf[j][0] = *(const bf16x8*)(krow + quad * 8);
      kf[j][1] = *(const bf16x8*)(krow + 32 + quad * 8);
    }
  };

  bf16x8 ka[4][2], kbuf2[4][2];

  // ======== prefix tile (keys 0..15, causal) ========
  {
    const u16* krow = kb + base + (size_t)l16 * 64;   // keys 0..15 (A-operand m=key)
    bf16x8 pk0 = *(const bf16x8*)(krow + quad * 8);
    bf16x8 pk1 = *(const bf16x8*)(krow + 32 + quad * 8);
    loadK(lo << 6, ka);                               // prefetch first window tile

    #pragma unroll
    for (int i = 0; i < 2; ++i) {
      f32x4 t4 = {};
      t4 = MFMA16(pk0, bq[i][0], t4, 0, 0, 0);
      t4 = MFMA16(pk1, bq[i][1], t4, 0, 0, 0);
      int row = i * 16 + l16;                          // query row
      int qpos = t0 + row;
      fpu p[4];
      #pragma unroll
      for (int r = 0; r < 4; ++r) {
        int kpos = quad * 4 + r;
        p[r].f = exp2f(kpos <= qpos ? t4[r] : -1e30f);
      }
      uint2 w;
      w.x = (p[1].u & 0xffff0000u) | (p[0].u >> 16);
      w.y = (p[3].u & 0xffff0000u) | (p[2].u >> 16);
      *(uint2*)&Ps[row * 64 + ((quad ^ l16) & 15) * 4] = w;          // keys quad*4..+3
      uint2 z = {0u, 0u};
      *(uint2*)&Ps[row * 64 + (((4 + quad) ^ l16) & 15) * 4] = z;    // keys 16..31 := 0
    }
    // PV (h=0 half only: keys 0..31, upper 16 zeroed)
    #pragma unroll
    for (int i = 0; i < 2; ++i) {
      int row = i * 16 + l16;
      uint2 r0 = *(uint2*)&Ps[row * 64 + (((2 * quad) ^ l16) & 15) * 4];
      uint2 r1 = *(uint2*)&Ps[row * 64 + (((2 * quad + 1) ^ l16) & 15) * 4];
      union { uint4 u; bf16x8 v; } cc; cc.u = make_uint4(r0.x, r0.y, r1.x, r1.y);
      bf16x8 ap = cc.v;
      lacc[i] = MFMA16(ap, ones, lacc[i], 0, 0, 0);
      #pragma unroll
      for (int jd = 0; jd < 4; ++jd) {
        bf16x8 bv = *(const bf16x8*)&vt[base + (size_t)(jd * 16 + l16) * 4096 + quad * 8];
        oacc[i][jd] = MFMA16(ap, bv, oacc[i][jd], 0, 0, 0);
      }
    }
  }

  // ======== sliding-window tiles ========
  auto tilec = [&](int kb0, bf16x8 (&kf)[4][2]) {
    const bool full = (kb0 >= 16) && (kb0 + 63 <= t0) && (kb0 >= t0 + 31 - 511);
    // S^T = K Q^T, mask, exp, packed store
    #pragma unroll
    for (int j = 0; j < 4; ++j) {
      #pragma unroll
      for (int i = 0; i < 2; ++i) {
        f32x4 t4 = {};
        t4 = MFMA16(kf[j][0], bq[i][0], t4, 0, 0, 0);
        t4 = MFMA16(kf[j][1], bq[i][1], t4, 0, 0, 0);
        int row = i * 16 + l16;
        int qpos = t0 + row;
        fpu p[4];
        #pragma unroll
        for (int r = 0; r < 4; ++r) {
          float v = t4[r];
          if (!full) {
            int kpos = kb0 + j * 16 + quad * 4 + r;
            int diff = qpos - kpos;
            bool ok = (diff >= 0) && (diff < 512) && (kpos >= 16);
            v = ok ? v : -1e30f;
          }
          p[r].f = exp2f(v);
        }
        uint2 w;
        w.x = (p[1].u & 0xffff0000u) | (p[0].u >> 16);
        w.y = (p[3].u & 0xffff0000u) | (p[2].u >> 16);
        *(uint2*)&Ps[row * 64 + (((j * 4 + quad) ^ l16) & 15) * 4] = w;
      }
    }
    // PV + l accumulation
    #pragma unroll
    for (int i = 0; i < 2; ++i) {
      int row = i * 16 + l16;
      #pragma unroll
      for (int h = 0; h < 2; ++h) {
        int g0 = h * 8 + 2 * quad;
        uint2 r0 = *(uint2*)&Ps[row * 64 + ((g0 ^ l16) & 15) * 4];
        uint2 r1 = *(uint2*)&Ps[row * 64 + (((g0 + 1) ^ l16) & 15) * 4];
        union { uint4 u; bf16x8 v; } cc; cc.u = make_uint4(r0.x, r0.y, r1.x, r1.y);
        bf16x8 ap = cc.v;
        lacc[i] = MFMA16(ap, ones, lacc[i], 0, 0, 0);
        #pragma unroll
        for (int jd = 0; jd < 4; ++jd) {
          bf16x8 bv = *(const bf16x8*)&vt[base + (size_t)(jd * 16 + l16) * 4096 + kb0 + h * 32 + quad * 8];
          oacc[i][jd] = MFMA16(ap, bv, oacc[i][jd], 0, 0, 0);
        }
      }
    }
  };

  for (int t = lo; t <= hi; t += 2) {
    if (t + 1 <= hi) loadK((t + 1) << 6, kbuf2);
    tilec(t << 6, ka);
    if (t + 1 <= hi) {
      if (t + 2 <= hi) loadK((t + 2) << 6, ka);
      tilec((t + 1) << 6, kbuf2);
    }
  }

  // ---- epilogue: O/l -> bf16 [B,S,H*64], granule-swizzled for GEMM3 staging ----
  const int b = bh >> 4, h = bh & 15;
  #pragma unroll
  for (int i = 0; i < 2; ++i) {
    #pragma unroll
    for (int r = 0; r < 4; ++r) {
      float inv = 1.f / lacc[i][r];
      int srow = t0 + i * 16 + quad * 4 + r;
      size_t rowoff = ((size_t)(b * 4096 + srow)) * 1024 + h * 64;
      #pragma unroll
      for (int jd = 0; jd < 4; ++jd) {
        int g = ((jd * 2 + (l16 >> 3)) ^ srow) & 7;
        ob[rowoff + (g << 3) + (l16 & 7)] = f2bf(oacc[i][jd][r] * inv);
      }
    }
  }
}

// ---------------- launch ----------------

extern "C" void kernel_launch(void* const* d_in, const int* in_sizes, int n_in,
                              void* d_out, int out_size, void* d_ws, size_t ws_size,
                              hipStream_t stream) {
  const float* x    = (const float*)d_in[0];
  const float* wqkv = (const float*)d_in[1];
  const float* wout = (const float*)d_in[2];
  float* out = (float*)d_out;

  u16* ws    = (u16*)d_ws;
  u16* xb    = ws;                                   // 8192*1024  (reused as obuf)
  u16* wqkvb = xb + (size_t)8192 * 1024;             // 3072*1024
  u16* woutb = wqkvb + (size_t)3072 * 1024;          // 1024*1024
  u16* qbuf  = woutb + (size_t)1024 * 1024;          // [2,16,4096,64]
  u16* kbuf  = qbuf + (size_t)8388608;
  u16* vbuf  = kbuf + (size_t)8388608;
  u16* vtb   = vbuf + (size_t)8388608;               // [2,16,64,4096]
  u16* obuf  = xb;                                   // alias: xb dead after gemm1

  cast_all_kernel<<<12288, 256, 0, stream>>>(x, wqkv, wout, ws);

  gemm_bt<1><<<dim3(24, 64), 256, 0, stream>>>(xb, wqkvb, nullptr, qbuf, kbuf, vbuf,
                                               8192, 3072, 1024);
  transpose_v<<<2048, 256, 0, stream>>>(vbuf, vtb);
  attn_kernel<<<4096, 64, 0, stream>>>(qbuf, kbuf, vtb, obuf);
  gemm_bt<0><<<dim3(8, 64), 256, 0, stream>>>(obuf, woutb, out, nullptr, nullptr, nullptr,
                                              8192, 1024, 1024);
}